// Round 4
// baseline (300.460 us; speedup 1.0000x reference)
//
#include <hip/hip_runtime.h>
#include <hip/hip_bf16.h>
#include <stdint.h>

#define B_ROWS 16384
#define D_IN   512
#define H_DIM  1024
#define K_TOT  1536
#define NT     24          // K-tiles of 64
#define NIT    12          // main-loop iterations (2 tiles each)

typedef __attribute__((ext_vector_type(8)))  short bf16x8;
typedef __attribute__((ext_vector_type(16))) float f32x16;
typedef __attribute__((ext_vector_type(4)))  float float4v;
typedef __attribute__((ext_vector_type(8)))  unsigned short u16x8;

__device__ __forceinline__ unsigned short f2bf(float f) {
    uint32_t u = __float_as_uint(f);
    u = (u + 0x7FFFu + ((u >> 16) & 1u)) >> 16;   // RNE
    return (unsigned short)u;
}

// ---------------------------------------------------------------------------
// A[r][k] bf16 : k in [0,512) = x[r][k] ; k in [512,1536) = h_old[r][k-512]
// ---------------------------------------------------------------------------
__global__ void cvt_A(const float* __restrict__ x, const float* __restrict__ h,
                      unsigned short* __restrict__ A) {
    int t   = blockIdx.x * blockDim.x + threadIdx.x;
    int row = t / 192;
    int seg = t % 192;
    const float* src;
    if (seg < 64) src = x + (size_t)row * D_IN + seg * 8;
    else          src = h + (size_t)row * H_DIM + (seg - 64) * 8;
    float4v v0 = *(const float4v*)(src);
    float4v v1 = *(const float4v*)(src + 4);
    u16x8 o;
    o[0] = f2bf(v0[0]); o[1] = f2bf(v0[1]); o[2] = f2bf(v0[2]); o[3] = f2bf(v0[3]);
    o[4] = f2bf(v1[0]); o[5] = f2bf(v1[1]); o[6] = f2bf(v1[2]); o[7] = f2bf(v1[3]);
    *(u16x8*)(A + (size_t)row * K_TOT + seg * 8) = o;
}

// ---------------------------------------------------------------------------
// Bg[c][k] bf16, c in [0,4096): gate-interleaved columns, granularity 64:
//   c = (h>>6)*256 + gate*64 + (h&63)   ->  gate=(c>>6)&3, h=((c>>8)<<6)|(c&63)
// ---------------------------------------------------------------------------
__global__ void cvt_B(const float* __restrict__ Ui, const float* __restrict__ Uf,
                      const float* __restrict__ Uo, const float* __restrict__ Uc,
                      const float* __restrict__ Wi, const float* __restrict__ Wf,
                      const float* __restrict__ Wo, const float* __restrict__ Wc,
                      unsigned short* __restrict__ Bg) {
    int t  = blockIdx.x * blockDim.x + threadIdx.x;
    int c  = t / 192;
    int k8 = t % 192;
    int g  = (c >> 6) & 3;
    int h  = ((c >> 8) << 6) | (c & 63);
    const float* up = (g == 0) ? Ui : (g == 1) ? Uf : (g == 2) ? Uo : Uc;
    const float* wp = (g == 0) ? Wi : (g == 1) ? Wf : (g == 2) ? Wo : Wc;
    int k = k8 * 8;
    u16x8 o;
    if (k < 512) {
        const float* s = up + (size_t)k * H_DIM + h;
        #pragma unroll
        for (int i = 0; i < 8; ++i) o[i] = f2bf(s[(size_t)i * H_DIM]);
    } else {
        const float* s = wp + (size_t)(k - 512) * H_DIM + h;
        #pragma unroll
        for (int i = 0; i < 8; ++i) o[i] = f2bf(s[(size_t)i * H_DIM]);
    }
    *(u16x8*)(Bg + (size_t)c * K_TOT + k) = o;
}

__global__ void cvt_bias(const float* __restrict__ Uib, const float* __restrict__ Ufb,
                         const float* __restrict__ Uob, const float* __restrict__ Ucb,
                         const float* __restrict__ Wib, const float* __restrict__ Wfb,
                         const float* __restrict__ Wob, const float* __restrict__ Wcb,
                         float* __restrict__ bias) {
    int t = blockIdx.x * blockDim.x + threadIdx.x;
    int g = t >> 10, h = t & 1023;
    const float* ub = (g == 0) ? Uib : (g == 1) ? Ufb : (g == 2) ? Uob : Ucb;
    const float* wb = (g == 0) ? Wib : (g == 1) ? Wfb : (g == 2) ? Wob : Wcb;
    bias[t] = ub[h] + wb[h];
}

// ---------------------------------------------------------------------------
// 256x256 GEMM, mfma_f32_32x32x16_bf16, 2 phases/tile, counted vmcnt.
// Waves: wm = wv>>1 (64 rows), wn = wv&1 (128 cols). Per wave: 2m x 4n frags.
// LDS: buf*65536 + mat*32768; region = 256 phys rows x 128 B (full K=64),
//   byte(pr,kgrp) = pr*128 + ((kgrp ^ (pr&7))<<4). Halves = phys rows 0-127/128-255.
// A phys row = matrix row (identity). B phys row -> matrix col:
//   col(pr) = (pr>>7)*128 + ((pr>>5)&1)*64 + ((pr>>6)&1)*32 + (pr&31)
//   (so read-set of ph0 {nn0,1} = phys half0, ph1 {nn2,3} = half1).
// Staging (global_load_lds, linear dest): per-lane source row/kg realize swizzle.
// Schedule: s.ph0 reads A(full)+B.h0, stages (s+1).h1; s.ph1 reads B.h1 (A in
// regs), stages (s+2).h0. Gates: ph0-end vmcnt(8), ph1-end vmcnt(6). Never 0.
// ---------------------------------------------------------------------------
__global__ __launch_bounds__(512, 2) void lstm_gemm(
        const unsigned short* __restrict__ Ag, const unsigned short* __restrict__ Bg,
        const float* __restrict__ bias, const float* __restrict__ c_old,
        float* __restrict__ out) {
    __shared__ __align__(1024) char lds[131072];

    const int tid = threadIdx.x;
    const int l   = tid & 63;
    const int wv  = tid >> 6;
    const int wm  = wv >> 1;      // 0..3
    const int wn  = wv & 1;       // 0..1

    // XCD-aware swizzle (R3's 8bm x 4bn chunks, bijective: 1024 = 64bm x 16bn)
    const int orig = blockIdx.x;
    const int xcd  = orig & 7;
    const int jj   = orig >> 3;
    const int bn   = (xcd & 3) * 4 + (jj & 3);     // 0..15
    const int bm   = (xcd >> 2) * 32 + (jj >> 2);  // 0..63

    // ---- staging source lanes (pre-swizzled global, rule 21) ----
    const int kg  = (l & 7) ^ (l >> 3);
    const int pr0 = wv * 16 + (l >> 3);            // half-local phys row, i=0
    const int pr1 = pr0 + 8;                       // i=1
    const unsigned short* aP0 = Ag + (size_t)(bm * 256 + pr0) * K_TOT + kg * 8;
    const unsigned short* aP1 = Ag + (size_t)(bm * 256 + pr1) * K_TOT + kg * 8;
    const int cB0 = ((pr0 >> 5) & 1) * 64 + ((pr0 >> 6) & 1) * 32 + (pr0 & 31);
    const int cB1 = ((pr1 >> 5) & 1) * 64 + ((pr1 >> 6) & 1) * 32 + (pr1 & 31);
    const unsigned short* bP0 = Bg + (size_t)(bn * 256 + cB0) * K_TOT + kg * 8;
    const unsigned short* bP1 = Bg + (size_t)(bn * 256 + cB1) * K_TOT + kg * 8;

    // ---- swizzled LDS read offsets ----
    const int r31 = l & 31;
    const int h5  = l >> 5;
    int aoffs[2][4], boffs[4][4];
    #pragma unroll
    for (int mm = 0; mm < 2; ++mm) {
        int pr = wm * 64 + mm * 32 + r31;
        #pragma unroll
        for (int ks = 0; ks < 4; ++ks)
            aoffs[mm][ks] = pr * 128 + (((ks * 2 + h5) ^ (pr & 7)) << 4);
    }
    #pragma unroll
    for (int nn = 0; nn < 4; ++nn) {
        int pr = (nn >> 1) * 128 + wn * 64 + (nn & 1) * 32 + r31;
        #pragma unroll
        for (int ks = 0; ks < 4; ++ks)
            boffs[nn][ks] = pr * 128 + (((ks * 2 + h5) ^ (pr & 7)) << 4);
    }

#define STAGE2(TILE, HF, BUF) do {                                                  \
    size_t _so = (size_t)((HF) * 128) * K_TOT + (TILE) * 64;                        \
    char* _da = (char*)lds + (BUF) * 65536 + (HF) * 16384 + wv * 2048;              \
    char* _db = _da + 32768;                                                        \
    __builtin_amdgcn_global_load_lds(                                               \
        (const __attribute__((address_space(1))) void*)(aP0 + _so),                 \
        (__attribute__((address_space(3))) void*)_da, 16, 0, 0);                    \
    __builtin_amdgcn_global_load_lds(                                               \
        (const __attribute__((address_space(1))) void*)(aP1 + _so),                 \
        (__attribute__((address_space(3))) void*)(_da + 1024), 16, 0, 0);           \
    __builtin_amdgcn_global_load_lds(                                               \
        (const __attribute__((address_space(1))) void*)(bP0 + _so),                 \
        (__attribute__((address_space(3))) void*)_db, 16, 0, 0);                    \
    __builtin_amdgcn_global_load_lds(                                               \
        (const __attribute__((address_space(1))) void*)(bP1 + _so),                 \
        (__attribute__((address_space(3))) void*)(_db + 1024), 16, 0, 0);           \
} while (0)

    f32x16 acc[2][4] = {};
    bf16x8 aF[2][4];

#define PH0(BUF, STILE, SBUF) do {                                                  \
    const char* _Ab = (const char*)lds + (BUF) * 65536;                             \
    const char* _Bb = _Ab + 32768;                                                  \
    _Pragma("unroll") for (int mm = 0; mm < 2; ++mm)                                \
        _Pragma("unroll") for (int ks = 0; ks < 4; ++ks)                            \
            aF[mm][ks] = *(const bf16x8*)(_Ab + aoffs[mm][ks]);                     \
    bf16x8 _b[2][4];                                                                \
    _Pragma("unroll") for (int nn = 0; nn < 2; ++nn)                                \
        _Pragma("unroll") for (int ks = 0; ks < 4; ++ks)                            \
            _b[nn][ks] = *(const bf16x8*)(_Bb + boffs[nn][ks]);                     \
    STAGE2(STILE, 1, SBUF);                                                         \
    __builtin_amdgcn_s_setprio(1);                                                  \
    _Pragma("unroll") for (int ks = 0; ks < 4; ++ks)                                \
        _Pragma("unroll") for (int mm = 0; mm < 2; ++mm)                            \
            _Pragma("unroll") for (int nn = 0; nn < 2; ++nn)                        \
                acc[mm][nn] = __builtin_amdgcn_mfma_f32_32x32x16_bf16(              \
                    aF[mm][ks], _b[nn][ks], acc[mm][nn], 0, 0, 0);                  \
    __builtin_amdgcn_s_setprio(0);                                                  \
    asm volatile("s_waitcnt vmcnt(8)\ns_barrier" ::: "memory");                     \
} while (0)

#define PH1(BUF, STILE, SBUF) do {                                                  \
    const char* _Bb = (const char*)lds + (BUF) * 65536 + 32768;                     \
    bf16x8 _b[2][4];                                                                \
    _Pragma("unroll") for (int nn = 0; nn < 2; ++nn)                                \
        _Pragma("unroll") for (int ks = 0; ks < 4; ++ks)                            \
            _b[nn][ks] = *(const bf16x8*)(_Bb + boffs[nn + 2][ks]);                 \
    STAGE2(STILE, 0, SBUF);                                                         \
    __builtin_amdgcn_s_setprio(1);                                                  \
    _Pragma("unroll") for (int ks = 0; ks < 4; ++ks)                                \
        _Pragma("unroll") for (int mm = 0; mm < 2; ++mm)                            \
            _Pragma("unroll") for (int nn = 0; nn < 2; ++nn)                        \
                acc[mm][nn + 2] = __builtin_amdgcn_mfma_f32_32x32x16_bf16(          \
                    aF[mm][ks], _b[nn][ks], acc[mm][nn + 2], 0, 0, 0);              \
    __builtin_amdgcn_s_setprio(0);                                                  \
    asm volatile("s_waitcnt vmcnt(6)\ns_barrier" ::: "memory");                     \
} while (0)

    // ---- prologue: T0.h0 -> buf0, T0.h1 -> buf0, T1.h0 -> buf1 (12 loads) ----
    STAGE2(0, 0, 0);
    STAGE2(0, 1, 0);
    STAGE2(1, 0, 1);
    asm volatile("s_waitcnt vmcnt(6)\ns_barrier" ::: "memory");

    // ---- main loop: tiles 2i (buf0), 2i+1 (buf1) ----
    #pragma unroll 1
    for (int i = 0; i < NIT; ++i) {
        const int t1 = 2 * i + 1;
        int t2 = 2 * i + 2; if (t2 >= NT) t2 -= NT;   // wrapped stagings never read
        int t3 = 2 * i + 3; if (t3 >= NT) t3 -= NT;
        PH0(0, t1, 1);      // compute T(2i).ph0 ; stage (2i+1).h1 -> buf1
        PH1(0, t2, 0);      //          .ph1     ; stage (2i+2).h0 -> buf0
        PH0(1, t2, 0);      // compute T(2i+1).ph0; stage (2i+2).h1 -> buf0
        PH1(1, t3, 1);      //          .ph1     ; stage (2i+3).h0 -> buf1
    }

    // ---- fused LSTM epilogue: 4 gates = 4 n-frags, all in-lane ----
    const int hh  = bn * 64 + wn * 32 + r31;
    const float bi  = bias[hh];
    const float bff = bias[1024 + hh];
    const float bo  = bias[2048 + hh];
    const float bc  = bias[3072 + hh];

    #pragma unroll
    for (int mm = 0; mm < 2; ++mm) {
        const int rb = bm * 256 + wm * 64 + mm * 32 + 4 * h5;
        #pragma unroll
        for (int r = 0; r < 16; ++r) {
            const int row = rb + (r & 3) + 8 * (r >> 2);
            float iv = acc[mm][0][r] + bi;
            float fv = acc[mm][1][r] + bff;
            float ov = acc[mm][2][r] + bo;
            float gv = acc[mm][3][r] + bc;
            float it = 1.f / (1.f + __expf(-iv));
            float ft = 1.f / (1.f + __expf(-fv));
            float ot = 1.f / (1.f + __expf(-ov));
            float gt = 1.f - 2.f / (1.f + __expf(2.f * gv));
            float co = c_old[(size_t)row * H_DIM + hh];
            float cn = it * gt + ft * co;
            float th = 1.f - 2.f / (1.f + __expf(2.f * cn));
            out[(size_t)row * H_DIM + hh] = ot * th;                          // h_new
            out[(size_t)B_ROWS * H_DIM + (size_t)row * H_DIM + hh] = cn;      // c
        }
    }
#undef PH0
#undef PH1
#undef STAGE2
}

extern "C" void kernel_launch(void* const* d_in, const int* in_sizes, int n_in,
                              void* d_out, int out_size, void* d_ws, size_t ws_size,
                              hipStream_t stream) {
    const float* x  = (const float*)d_in[0];
    const float* h0 = (const float*)d_in[1];
    const float* c0 = (const float*)d_in[2];
    const float* Uw[4] = {(const float*)d_in[3],  (const float*)d_in[5],
                          (const float*)d_in[7],  (const float*)d_in[9]};
    const float* Ub[4] = {(const float*)d_in[4],  (const float*)d_in[6],
                          (const float*)d_in[8],  (const float*)d_in[10]};
    const float* Ww[4] = {(const float*)d_in[11], (const float*)d_in[13],
                          (const float*)d_in[15], (const float*)d_in[17]};
    const float* Wb[4] = {(const float*)d_in[12], (const float*)d_in[14],
                          (const float*)d_in[16], (const float*)d_in[18]};

    unsigned short* Ag = (unsigned short*)d_ws;
    unsigned short* Bg = Ag + (size_t)B_ROWS * K_TOT;
    float* bias        = (float*)(Bg + (size_t)4096 * K_TOT);
    float* out         = (float*)d_out;

    cvt_A<<<12288, 256, 0, stream>>>(x, h0, Ag);
    cvt_B<<<3072, 256, 0, stream>>>(Uw[0], Uw[1], Uw[2], Uw[3],
                                    Ww[0], Ww[1], Ww[2], Ww[3], Bg);
    cvt_bias<<<16, 256, 0, stream>>>(Ub[0], Ub[1], Ub[2], Ub[3],
                                     Wb[0], Wb[1], Wb[2], Wb[3], bias);
    lstm_gemm<<<1024, 512, 0, stream>>>(Ag, Bg, bias, c0, out);
}

// Round 5
// 274.116 us; speedup vs baseline: 1.0961x; 1.0961x over previous
//
#include <hip/hip_runtime.h>
#include <hip/hip_bf16.h>
#include <stdint.h>

#define B_ROWS 16384
#define D_IN   512
#define H_DIM  1024
#define K_TOT  1536
#define NKT    48          // K-tiles of 32
#define NIT    12          // main loop iterations (4 phases each)

typedef __attribute__((ext_vector_type(8)))  short bf16x8;
typedef __attribute__((ext_vector_type(16))) float f32x16;
typedef __attribute__((ext_vector_type(4)))  float float4v;
typedef __attribute__((ext_vector_type(8)))  unsigned short u16x8;

__device__ __forceinline__ unsigned short f2bf(float f) {
    uint32_t u = __float_as_uint(f);
    u = (u + 0x7FFFu + ((u >> 16) & 1u)) >> 16;   // RNE
    return (unsigned short)u;
}

// ---------------------------------------------------------------------------
// Ag in FRAGMENT-LINEAR TILED order:
//   granule g = ((bm*48 + tile)*16 + chunk)*64 + lane   (16 B each)
//   lane l, elem j: row = bm*256 + (chunk>>1)*32 + (l&31)
//                   k   = tile*32 + (chunk&1)*16 + (l>>5)*8 + j
//   A[row][k] = k<512 ? x[row][k] : h_old[row][k-512]
// One thread per granule; 3,145,728 threads. Writes fully linear; each 256-thr
// block consumes 64 rows x one 128B line exactly once.
// ---------------------------------------------------------------------------
__global__ void cvt_A(const float* __restrict__ x, const float* __restrict__ h,
                      unsigned short* __restrict__ Ag) {
    int t     = blockIdx.x * blockDim.x + threadIdx.x;
    int lane  = t & 63;
    int chunk = (t >> 6) & 15;
    int rest  = t >> 10;            // bm*48 + tile
    int tile  = rest % 48;
    int bm    = rest / 48;
    int row   = bm * 256 + (chunk >> 1) * 32 + (lane & 31);
    int k     = tile * 32 + (chunk & 1) * 16 + (lane >> 5) * 8;
    const float* src = (k < 512) ? (x + (size_t)row * D_IN + k)
                                 : (h + (size_t)row * H_DIM + (k - 512));
    float4v v0 = *(const float4v*)(src);
    float4v v1 = *(const float4v*)(src + 4);
    u16x8 o;
    o[0] = f2bf(v0[0]); o[1] = f2bf(v0[1]); o[2] = f2bf(v0[2]); o[3] = f2bf(v0[3]);
    o[4] = f2bf(v1[0]); o[5] = f2bf(v1[1]); o[6] = f2bf(v1[2]); o[7] = f2bf(v1[3]);
    *(u16x8*)(Ag + (size_t)t * 8) = o;
}

// ---------------------------------------------------------------------------
// Bg fragment-linear tiled, gate-interleaved cols (granularity 32):
//   col c = (h>>5)*128 + gate*32 + (h&31)  ->  gate=(c>>5)&3, h=((c>>7)<<5)|(c&31)
//   granule g = ((bn*48 + tile)*16 + chunk)*64 + lane
//   lane l, elem j: c = bn*256 + (chunk>>1)*32 + (l&31)
//                   k = tile*32 + (chunk&1)*16 + (l>>5)*8 + j
//   B[c][k] = k<512 ? Ugate_w[k][h] : Wgate_w[k-512][h]
// ---------------------------------------------------------------------------
__global__ void cvt_B(const float* __restrict__ Ui, const float* __restrict__ Uf,
                      const float* __restrict__ Uo, const float* __restrict__ Uc,
                      const float* __restrict__ Wi, const float* __restrict__ Wf,
                      const float* __restrict__ Wo, const float* __restrict__ Wc,
                      unsigned short* __restrict__ Bg) {
    int t     = blockIdx.x * blockDim.x + threadIdx.x;
    int lane  = t & 63;
    int chunk = (t >> 6) & 15;
    int rest  = t >> 10;            // bn*48 + tile
    int tile  = rest % 48;
    int bn    = rest / 48;
    int c     = bn * 256 + (chunk >> 1) * 32 + (lane & 31);
    int g     = (c >> 5) & 3;
    int hcol  = ((c >> 7) << 5) | (c & 31);
    int k     = tile * 32 + (chunk & 1) * 16 + (lane >> 5) * 8;
    const float* up = (g == 0) ? Ui : (g == 1) ? Uf : (g == 2) ? Uo : Uc;
    const float* wp = (g == 0) ? Wi : (g == 1) ? Wf : (g == 2) ? Wo : Wc;
    u16x8 o;
    if (k < 512) {
        const float* s = up + (size_t)k * H_DIM + hcol;
        #pragma unroll
        for (int i = 0; i < 8; ++i) o[i] = f2bf(s[(size_t)i * H_DIM]);
    } else {
        const float* s = wp + (size_t)(k - 512) * H_DIM + hcol;
        #pragma unroll
        for (int i = 0; i < 8; ++i) o[i] = f2bf(s[(size_t)i * H_DIM]);
    }
    *(u16x8*)(Bg + (size_t)t * 8) = o;
}

__global__ void cvt_bias(const float* __restrict__ Uib, const float* __restrict__ Ufb,
                         const float* __restrict__ Uob, const float* __restrict__ Ucb,
                         const float* __restrict__ Wib, const float* __restrict__ Wfb,
                         const float* __restrict__ Wob, const float* __restrict__ Wcb,
                         float* __restrict__ bias) {
    int t = blockIdx.x * blockDim.x + threadIdx.x;
    int g = t >> 10, h = t & 1023;
    const float* ub = (g == 0) ? Uib : (g == 1) ? Ufb : (g == 2) ? Uob : Ucb;
    const float* wb = (g == 0) ? Wib : (g == 1) ? Wfb : (g == 2) ? Wob : Wcb;
    bias[t] = ub[h] + wb[h];
}

// ---------------------------------------------------------------------------
// 256x256 GEMM, mfma_f32_32x32x16_bf16, 4-deep LDS ring, fragment-linear LDS.
// 8 waves: wm = wv>>1 (64 rows), wn = wv&1 (128 cols); per-wave 2m x 4n frags.
// LDS: 4 slots x (A 16KB + B 16KB). Slot layout = 16 chunks x 1KB each side;
//   chunkA = (wm*2+mm)*2+ks, chunkB = (wn*4+nn)*2+ks; byte = chunk*1024 + l*16.
// All ds_read_b128 are 64 consecutive granules -> zero bank conflicts.
// Staging: wave wv copies chunks {2wv, 2wv+1} of A and B (4 glds, linear src
// and dest). Phase t: read slot t&3, stage tile t+3 -> slot (t+3)&3,
// vmcnt(8) + barrier (waits exactly tile t+1's 4 loads; 3-phase latency hide).
// ---------------------------------------------------------------------------
__global__ __launch_bounds__(512, 2) void lstm_gemm(
        const unsigned short* __restrict__ Ag, const unsigned short* __restrict__ Bg,
        const float* __restrict__ bias, const float* __restrict__ c_old,
        float* __restrict__ out) {
    __shared__ __align__(1024) char lds[131072];

    const int tid = threadIdx.x;
    const int l   = tid & 63;
    const int wv  = tid >> 6;
    const int wm  = wv >> 1;      // 0..3
    const int wn  = wv & 1;       // 0..1

    // XCD-aware swizzle: per XCD 8bm x 4bn chunks (R3 mapping, FETCH ~190MB)
    const int orig = blockIdx.x;
    const int xcd  = orig & 7;
    const int jj   = orig >> 3;
    const int bn   = (xcd & 3) * 4 + (jj & 3);     // 0..15
    const int bm   = (xcd >> 2) * 32 + (jj >> 2);  // 0..63

    // staging sources: tile block = 16 chunks * 512 ushorts = 8192 ushorts
    const unsigned short* aT = Ag + (size_t)(wv * 2) * 512 + l * 8;
    const unsigned short* bT = Bg + (size_t)(wv * 2) * 512 + l * 8;
    const size_t aTileBase = (size_t)bm * 48 * 8192;
    const size_t bTileBase = (size_t)bn * 48 * 8192;

#define GLDS(SRC, DST) __builtin_amdgcn_global_load_lds(                            \
        (const __attribute__((address_space(1))) void*)(SRC),                       \
        (__attribute__((address_space(3))) void*)(DST), 16, 0, 0)

#define STAGE(ST, SLOT) do {                                                        \
    const unsigned short* _a = aT + aTileBase + (size_t)(ST) * 8192;                \
    const unsigned short* _b = bT + bTileBase + (size_t)(ST) * 8192;                \
    char* _da = (char*)lds + (SLOT) * 32768 + (wv * 2) * 1024;                      \
    char* _db = _da + 16384;                                                        \
    GLDS(_a,       _da);        GLDS(_a + 512, _da + 1024);                         \
    GLDS(_b,       _db);        GLDS(_b + 512, _db + 1024);                         \
} while (0)

    f32x16 acc[2][4] = {};

#define PHASE(P, ST) do {                                                           \
    const char* _Ab = (const char*)lds + (P) * 32768 + wm * 4096 + l * 16;          \
    const char* _Bb = (const char*)lds + (P) * 32768 + 16384 + wn * 8192 + l * 16;  \
    bf16x8 aF[2][2], bF[4][2];                                                      \
    _Pragma("unroll") for (int mm = 0; mm < 2; ++mm)                                \
        _Pragma("unroll") for (int ks = 0; ks < 2; ++ks)                            \
            aF[mm][ks] = *(const bf16x8*)(_Ab + mm * 2048 + ks * 1024);             \
    _Pragma("unroll") for (int nn = 0; nn < 4; ++nn)                                \
        _Pragma("unroll") for (int ks = 0; ks < 2; ++ks)                            \
            bF[nn][ks] = *(const bf16x8*)(_Bb + nn * 2048 + ks * 1024);             \
    STAGE(ST, ((P) + 3) & 3);                                                       \
    __builtin_amdgcn_s_setprio(1);                                                  \
    _Pragma("unroll") for (int ks = 0; ks < 2; ++ks)                                \
        _Pragma("unroll") for (int mm = 0; mm < 2; ++mm)                            \
            _Pragma("unroll") for (int nn = 0; nn < 4; ++nn)                        \
                acc[mm][nn] = __builtin_amdgcn_mfma_f32_32x32x16_bf16(              \
                    aF[mm][ks], bF[nn][ks], acc[mm][nn], 0, 0, 0);                  \
    __builtin_amdgcn_s_setprio(0);                                                  \
    asm volatile("s_waitcnt vmcnt(8)\ns_barrier" ::: "memory");                     \
} while (0)

    // ---- prologue: stage tiles 0,1,2 into slots 0,1,2 ----
    STAGE(0, 0); STAGE(1, 1); STAGE(2, 2);
    asm volatile("s_waitcnt vmcnt(8)\ns_barrier" ::: "memory");

    // ---- main loop: 48 phases ----
    #pragma unroll 1
    for (int i = 0; i < NIT; ++i) {
        const int b4 = i * 4;
        int s0 = b4 + 3;
        int s1 = b4 + 4; if (s1 >= NKT) s1 -= NKT;   // wrapped stagings never read
        int s2 = b4 + 5; if (s2 >= NKT) s2 -= NKT;
        int s3 = b4 + 6; if (s3 >= NKT) s3 -= NKT;
        PHASE(0, s0);
        PHASE(1, s1);
        PHASE(2, s2);
        PHASE(3, s3);
    }
    asm volatile("s_waitcnt vmcnt(0)" ::: "memory");   // drain garbage stagings

    // ---- fused LSTM epilogue: gate = nn (in-lane), hh = (bn*2+wn)*32 + col ----
    const int r31 = l & 31;
    const int h5  = l >> 5;
    const int hh  = (bn * 2 + wn) * 32 + r31;
    const float bi  = bias[hh];
    const float bff = bias[1024 + hh];
    const float bo  = bias[2048 + hh];
    const float bc  = bias[3072 + hh];

    #pragma unroll
    for (int mm = 0; mm < 2; ++mm) {
        const int rb = bm * 256 + wm * 64 + mm * 32 + 4 * h5;
        #pragma unroll
        for (int r = 0; r < 16; ++r) {
            const int row = rb + (r & 3) + 8 * (r >> 2);
            float iv = acc[mm][0][r] + bi;
            float fv = acc[mm][1][r] + bff;
            float ov = acc[mm][2][r] + bo;
            float gv = acc[mm][3][r] + bc;
            float it = 1.f / (1.f + __expf(-iv));
            float ft = 1.f / (1.f + __expf(-fv));
            float ot = 1.f / (1.f + __expf(-ov));
            float gt = 1.f - 2.f / (1.f + __expf(2.f * gv));
            float co = c_old[(size_t)row * H_DIM + hh];
            float cn = it * gt + ft * co;
            float th = 1.f - 2.f / (1.f + __expf(2.f * cn));
            out[(size_t)row * H_DIM + hh] = ot * th;                          // h_new
            out[(size_t)B_ROWS * H_DIM + (size_t)row * H_DIM + hh] = cn;      // c
        }
    }
#undef PHASE
#undef STAGE
#undef GLDS
}

extern "C" void kernel_launch(void* const* d_in, const int* in_sizes, int n_in,
                              void* d_out, int out_size, void* d_ws, size_t ws_size,
                              hipStream_t stream) {
    const float* x  = (const float*)d_in[0];
    const float* h0 = (const float*)d_in[1];
    const float* c0 = (const float*)d_in[2];
    const float* Uw[4] = {(const float*)d_in[3],  (const float*)d_in[5],
                          (const float*)d_in[7],  (const float*)d_in[9]};
    const float* Ub[4] = {(const float*)d_in[4],  (const float*)d_in[6],
                          (const float*)d_in[8],  (const float*)d_in[10]};
    const float* Ww[4] = {(const float*)d_in[11], (const float*)d_in[13],
                          (const float*)d_in[15], (const float*)d_in[17]};
    const float* Wb[4] = {(const float*)d_in[12], (const float*)d_in[14],
                          (const float*)d_in[16], (const float*)d_in[18]};

    unsigned short* Ag = (unsigned short*)d_ws;                 // 48 MiB
    unsigned short* Bg = Ag + (size_t)B_ROWS * K_TOT;           // 12 MiB
    float* bias        = (float*)(Bg + (size_t)4096 * K_TOT);   // 16 KiB
    float* out         = (float*)d_out;

    cvt_A<<<12288, 256, 0, stream>>>(x, h0, Ag);
    cvt_B<<<3072, 256, 0, stream>>>(Uw[0], Uw[1], Uw[2], Uw[3],
                                    Ww[0], Ww[1], Ww[2], Ww[3], Bg);
    cvt_bias<<<16, 256, 0, stream>>>(Ub[0], Ub[1], Ub[2], Ub[3],
                                     Wb[0], Wb[1], Wb[2], Wb[3], bias);
    lstm_gemm<<<1024, 512, 0, stream>>>(Ag, Bg, bias, c0, out);
}

// Round 6
// 272.202 us; speedup vs baseline: 1.1038x; 1.0070x over previous
//
#include <hip/hip_runtime.h>
#include <hip/hip_bf16.h>
#include <stdint.h>

#define B_ROWS 16384
#define D_IN   512
#define H_DIM  1024
#define K_TOT  1536
#define NKT    48          // K-tiles of 32

typedef __attribute__((ext_vector_type(8)))  short bf16x8;
typedef __attribute__((ext_vector_type(16))) float f32x16;
typedef __attribute__((ext_vector_type(4)))  float float4v;
typedef __attribute__((ext_vector_type(8)))  unsigned short u16x8;

__device__ __forceinline__ unsigned short f2bf(float f) {
    uint32_t u = __float_as_uint(f);
    u = (u + 0x7FFFu + ((u >> 16) & 1u)) >> 16;   // RNE
    return (unsigned short)u;
}

// ---------------------------------------------------------------------------
// Ag in FRAGMENT-LINEAR TILED order (unchanged from R5):
//   granule g = ((bm*48 + tile)*16 + chunk)*64 + lane   (16 B each)
//   lane l, elem j: row = bm*256 + (chunk>>1)*32 + (l&31)
//                   k   = tile*32 + (chunk&1)*16 + (l>>5)*8 + j
// ---------------------------------------------------------------------------
__global__ void cvt_A(const float* __restrict__ x, const float* __restrict__ h,
                      unsigned short* __restrict__ Ag) {
    int t     = blockIdx.x * blockDim.x + threadIdx.x;
    int lane  = t & 63;
    int chunk = (t >> 6) & 15;
    int rest  = t >> 10;            // bm*48 + tile
    int tile  = rest % 48;
    int bm    = rest / 48;
    int row   = bm * 256 + (chunk >> 1) * 32 + (lane & 31);
    int k     = tile * 32 + (chunk & 1) * 16 + (lane >> 5) * 8;
    const float* src = (k < 512) ? (x + (size_t)row * D_IN + k)
                                 : (h + (size_t)row * H_DIM + (k - 512));
    float4v v0 = *(const float4v*)(src);
    float4v v1 = *(const float4v*)(src + 4);
    u16x8 o;
    o[0] = f2bf(v0[0]); o[1] = f2bf(v0[1]); o[2] = f2bf(v0[2]); o[3] = f2bf(v0[3]);
    o[4] = f2bf(v1[0]); o[5] = f2bf(v1[1]); o[6] = f2bf(v1[2]); o[7] = f2bf(v1[3]);
    *(u16x8*)(Ag + (size_t)t * 8) = o;
}

// ---------------------------------------------------------------------------
// Bg fragment-linear tiled, gate-interleaved cols (granularity 32):
//   col c = (h>>5)*128 + gate*32 + (h&31)
// ---------------------------------------------------------------------------
__global__ void cvt_B(const float* __restrict__ Ui, const float* __restrict__ Uf,
                      const float* __restrict__ Uo, const float* __restrict__ Uc,
                      const float* __restrict__ Wi, const float* __restrict__ Wf,
                      const float* __restrict__ Wo, const float* __restrict__ Wc,
                      unsigned short* __restrict__ Bg) {
    int t     = blockIdx.x * blockDim.x + threadIdx.x;
    int lane  = t & 63;
    int chunk = (t >> 6) & 15;
    int rest  = t >> 10;            // bn*48 + tile
    int tile  = rest % 48;
    int bn    = rest / 48;
    int c     = bn * 256 + (chunk >> 1) * 32 + (lane & 31);
    int g     = (c >> 5) & 3;
    int hcol  = ((c >> 7) << 5) | (c & 31);
    int k     = tile * 32 + (chunk & 1) * 16 + (lane >> 5) * 8;
    const float* up = (g == 0) ? Ui : (g == 1) ? Uf : (g == 2) ? Uo : Uc;
    const float* wp = (g == 0) ? Wi : (g == 1) ? Wf : (g == 2) ? Wo : Wc;
    u16x8 o;
    if (k < 512) {
        const float* s = up + (size_t)k * H_DIM + hcol;
        #pragma unroll
        for (int i = 0; i < 8; ++i) o[i] = f2bf(s[(size_t)i * H_DIM]);
    } else {
        const float* s = wp + (size_t)(k - 512) * H_DIM + hcol;
        #pragma unroll
        for (int i = 0; i < 8; ++i) o[i] = f2bf(s[(size_t)i * H_DIM]);
    }
    *(u16x8*)(Bg + (size_t)t * 8) = o;
}

__global__ void cvt_bias(const float* __restrict__ Uib, const float* __restrict__ Ufb,
                         const float* __restrict__ Uob, const float* __restrict__ Ucb,
                         const float* __restrict__ Wib, const float* __restrict__ Wfb,
                         const float* __restrict__ Wob, const float* __restrict__ Wcb,
                         float* __restrict__ bias) {
    int t = blockIdx.x * blockDim.x + threadIdx.x;
    int g = t >> 10, h = t & 1023;
    const float* ub = (g == 0) ? Uib : (g == 1) ? Ufb : (g == 2) ? Uob : Ucb;
    const float* wb = (g == 0) ? Wib : (g == 1) ? Wfb : (g == 2) ? Wob : Wcb;
    bias[t] = ub[h] + wb[h];
}

// ---------------------------------------------------------------------------
// 256x256 GEMM, mfma_f32_32x32x16_bf16, 5-deep LDS ring, fragment-linear LDS,
// m201-style phase skeleton: {12 ds_read ; 4 glds stage ; barrier ; lgkmcnt(0)
// ; setprio+16 MFMA ; barrier(+vmcnt(8) on ODD phases only)}.
// Ring invariant: phase t reads slot t%5, stages tile t+4 -> slot (t+4)%5 =
// (t-1)%5 (freed at t-1 end barrier). Gate at odd t leaves {t+3,t+4} = 8 loads
// outstanding => tiles <= t+2 landed, covering phases t+1, t+2.
// ---------------------------------------------------------------------------
__global__ __launch_bounds__(512, 2) void lstm_gemm(
        const unsigned short* __restrict__ Ag, const unsigned short* __restrict__ Bg,
        const float* __restrict__ bias, const float* __restrict__ c_old,
        float* __restrict__ out) {
    __shared__ __align__(1024) char lds[163840];   // 5 slots x 32 KiB

    const int tid = threadIdx.x;
    const int l   = tid & 63;
    const int wv  = tid >> 6;
    const int wm  = wv >> 1;      // 0..3
    const int wn  = wv & 1;       // 0..1

    // XCD-aware swizzle: per XCD 8bm x 4bn chunks
    const int orig = blockIdx.x;
    const int xcd  = orig & 7;
    const int jj   = orig >> 3;
    const int bn   = (xcd & 3) * 4 + (jj & 3);     // 0..15
    const int bm   = (xcd >> 2) * 32 + (jj >> 2);  // 0..63

    // staging sources: tile block = 16 chunks * 512 ushorts = 8192 ushorts
    const unsigned short* aT = Ag + (size_t)(wv * 2) * 512 + l * 8;
    const unsigned short* bT = Bg + (size_t)(wv * 2) * 512 + l * 8;
    const size_t aTileBase = (size_t)bm * 48 * 8192;
    const size_t bTileBase = (size_t)bn * 48 * 8192;

#define GLDS(SRC, DST) __builtin_amdgcn_global_load_lds(                            \
        (const __attribute__((address_space(1))) void*)(SRC),                       \
        (__attribute__((address_space(3))) void*)(DST), 16, 0, 0)

#define STAGE(ST, SLOT) do {                                                        \
    const unsigned short* _a = aT + aTileBase + (size_t)(ST) * 8192;                \
    const unsigned short* _b = bT + bTileBase + (size_t)(ST) * 8192;                \
    char* _da = (char*)lds + (SLOT) * 32768 + (wv * 2) * 1024;                      \
    char* _db = _da + 16384;                                                        \
    GLDS(_a,       _da);        GLDS(_a + 512, _da + 1024);                         \
    GLDS(_b,       _db);        GLDS(_b + 512, _db + 1024);                         \
} while (0)

    f32x16 acc[2][4] = {};

#define PHASE(SLOT, ST, SSLOT, GATE) do {                                           \
    const char* _Ab = (const char*)lds + (SLOT) * 32768 + wm * 4096 + l * 16;       \
    const char* _Bb = (const char*)lds + (SLOT) * 32768 + 16384 + wn * 8192 + l * 16;\
    bf16x8 aF[2][2], bF[4][2];                                                      \
    _Pragma("unroll") for (int mm = 0; mm < 2; ++mm)                                \
        _Pragma("unroll") for (int ks = 0; ks < 2; ++ks)                            \
            aF[mm][ks] = *(const bf16x8*)(_Ab + mm * 2048 + ks * 1024);             \
    _Pragma("unroll") for (int nn = 0; nn < 4; ++nn)                                \
        _Pragma("unroll") for (int ks = 0; ks < 2; ++ks)                            \
            bF[nn][ks] = *(const bf16x8*)(_Bb + nn * 2048 + ks * 1024);             \
    STAGE(ST, SSLOT);                                                               \
    asm volatile("s_barrier" ::: "memory");                                         \
    asm volatile("s_waitcnt lgkmcnt(0)" ::: "memory");                              \
    __builtin_amdgcn_sched_barrier(0);                                              \
    __builtin_amdgcn_s_setprio(1);                                                  \
    _Pragma("unroll") for (int ks = 0; ks < 2; ++ks)                                \
        _Pragma("unroll") for (int mm = 0; mm < 2; ++mm)                            \
            _Pragma("unroll") for (int nn = 0; nn < 4; ++nn)                        \
                acc[mm][nn] = __builtin_amdgcn_mfma_f32_32x32x16_bf16(              \
                    aF[mm][ks], bF[nn][ks], acc[mm][nn], 0, 0, 0);                  \
    __builtin_amdgcn_s_setprio(0);                                                  \
    if (GATE) { asm volatile("s_waitcnt vmcnt(8)\ns_barrier" ::: "memory"); }       \
    else      { asm volatile("s_barrier" ::: "memory"); }                           \
} while (0)

    // ---- prologue: stage tiles 0..3 into slots 0..3; drain to tiles 0,1 ----
    STAGE(0, 0); STAGE(1, 1); STAGE(2, 2); STAGE(3, 3);
    asm volatile("s_waitcnt vmcnt(8)\ns_barrier" ::: "memory");

    // ---- main loop: 4 iterations x 10 phases (tiles 10i .. 10i+9) ----
    #pragma unroll 1
    for (int i = 0; i < 4; ++i) {
        const int T = i * 10;
        PHASE(0, T + 4,  4, 0);
        PHASE(1, T + 5,  0, 1);
        PHASE(2, T + 6,  1, 0);
        PHASE(3, T + 7,  2, 1);
        PHASE(4, T + 8,  3, 0);
        PHASE(0, T + 9,  4, 1);
        PHASE(1, T + 10, 0, 0);
        PHASE(2, T + 11, 1, 1);
        PHASE(3, T + 12, 2, 0);
        PHASE(4, T + 13, 3, 1);
    }

    // ---- tail: phases 40..47 (stages 44..47 real, then dummies of tile 0) ----
    PHASE(0, 44, 4, 0);
    PHASE(1, 45, 0, 1);
    PHASE(2, 46, 1, 0);
    PHASE(3, 47, 2, 1);
    PHASE(4, 0,  3, 0);   // dummy stagings: slots already past last read
    PHASE(0, 0,  4, 1);
    PHASE(1, 0,  0, 0);
    PHASE(2, 0,  1, 1);

    asm volatile("s_waitcnt vmcnt(0)" ::: "memory");   // drain dummy stagings

    // ---- fused LSTM epilogue: gate = nn (in-lane), hh = (bn*2+wn)*32 + col ----
    const int r31 = l & 31;
    const int h5  = l >> 5;
    const int hh  = (bn * 2 + wn) * 32 + r31;
    const float bi  = bias[hh];
    const float bff = bias[1024 + hh];
    const float bo  = bias[2048 + hh];
    const float bc  = bias[3072 + hh];

    #pragma unroll
    for (int mm = 0; mm < 2; ++mm) {
        const int rb = bm * 256 + wm * 64 + mm * 32 + 4 * h5;
        #pragma unroll
        for (int r = 0; r < 16; ++r) {
            const int row = rb + (r & 3) + 8 * (r >> 2);
            float iv = acc[mm][0][r] + bi;
            float fv = acc[mm][1][r] + bff;
            float ov = acc[mm][2][r] + bo;
            float gv = acc[mm][3][r] + bc;
            float it = 1.f / (1.f + __expf(-iv));
            float ft = 1.f / (1.f + __expf(-fv));
            float ot = 1.f / (1.f + __expf(-ov));
            float gt = 1.f - 2.f / (1.f + __expf(2.f * gv));
            float co = c_old[(size_t)row * H_DIM + hh];
            float cn = it * gt + ft * co;
            float th = 1.f - 2.f / (1.f + __expf(2.f * cn));
            out[(size_t)row * H_DIM + hh] = ot * th;                          // h_new
            out[(size_t)B_ROWS * H_DIM + (size_t)row * H_DIM + hh] = cn;      // c
        }
    }
#undef PHASE
#undef STAGE
#undef GLDS
}

extern "C" void kernel_launch(void* const* d_in, const int* in_sizes, int n_in,
                              void* d_out, int out_size, void* d_ws, size_t ws_size,
                              hipStream_t stream) {
    const float* x  = (const float*)d_in[0];
    const float* h0 = (const float*)d_in[1];
    const float* c0 = (const float*)d_in[2];
    const float* Uw[4] = {(const float*)d_in[3],  (const float*)d_in[5],
                          (const float*)d_in[7],  (const float*)d_in[9]};
    const float* Ub[4] = {(const float*)d_in[4],  (const float*)d_in[6],
                          (const float*)d_in[8],  (const float*)d_in[10]};
    const float* Ww[4] = {(const float*)d_in[11], (const float*)d_in[13],
                          (const float*)d_in[15], (const float*)d_in[17]};
    const float* Wb[4] = {(const float*)d_in[12], (const float*)d_in[14],
                          (const float*)d_in[16], (const float*)d_in[18]};

    unsigned short* Ag = (unsigned short*)d_ws;                 // 48 MiB
    unsigned short* Bg = Ag + (size_t)B_ROWS * K_TOT;           // 12 MiB
    float* bias        = (float*)(Bg + (size_t)4096 * K_TOT);   // 16 KiB
    float* out         = (float*)d_out;

    cvt_A<<<12288, 256, 0, stream>>>(x, h0, Ag);
    cvt_B<<<3072, 256, 0, stream>>>(Uw[0], Uw[1], Uw[2], Uw[3],
                                    Ww[0], Ww[1], Ww[2], Ww[3], Bg);
    cvt_bias<<<16, 256, 0, stream>>>(Ub[0], Ub[1], Ub[2], Ub[3],
                                     Wb[0], Wb[1], Wb[2], Wb[3], bias);
    lstm_gemm<<<1024, 512, 0, stream>>>(Ag, Bg, bias, c0, out);
}